// Round 2
// baseline (982.156 us; speedup 1.0000x reference)
//
#include <hip/hip_runtime.h>

#define RR 7
#define EPSBN 1e-5f

typedef __attribute__((ext_vector_type(8))) __bf16 bf16x8;
typedef __attribute__((ext_vector_type(4))) float f32x4;

__device__ __forceinline__ float uhi2f(unsigned int u) {
    union { unsigned int i; float f; } c; c.i = u; return c.f;
}
__device__ __forceinline__ unsigned short f2b(float f) {
    union { float f; unsigned int i; } c; c.f = f;
    unsigned int x = c.i;
    return (unsigned short)((x + 0x7fffu + ((x >> 16) & 1u)) >> 16);
}

// ---------------- CSR build ----------------
__global__ void zero_i32_k(int* p, int n) {
    int i = blockIdx.x * 256 + threadIdx.x; if (i < n) p[i] = 0;
}
__global__ void hist_k(const int* __restrict__ dst, const int* __restrict__ et,
                       int* __restrict__ cnt, int ne) {
    int e = blockIdx.x * 256 + threadIdx.x;
    if (e < ne) atomicAdd(&cnt[dst[e] * RR + et[e]], 1);
}
__global__ void scan1_k(const int* __restrict__ cnt, int* __restrict__ bsum, int n) {
    __shared__ int sh[256];
    int base = blockIdx.x << 10;
    int s = 0;
    for (int i = threadIdx.x; i < 1024; i += 256) { int idx = base + i; if (idx < n) s += cnt[idx]; }
    sh[threadIdx.x] = s; __syncthreads();
    for (int off = 128; off > 0; off >>= 1) {
        if (threadIdx.x < off) sh[threadIdx.x] += sh[threadIdx.x + off];
        __syncthreads();
    }
    if (threadIdx.x == 0) bsum[blockIdx.x] = sh[0];
}
__global__ void scan2_k(int* __restrict__ bsum, int nb) {   // nb <= 1024
    __shared__ int sh[256];
    int t = threadIdx.x;
    int v[4]; int loc = 0;
#pragma unroll
    for (int i = 0; i < 4; ++i) { int idx = t * 4 + i; v[i] = (idx < nb) ? bsum[idx] : 0; loc += v[i]; }
    sh[t] = loc; __syncthreads();
    for (int off = 1; off < 256; off <<= 1) {
        int x = (t >= off) ? sh[t - off] : 0;
        __syncthreads();
        sh[t] += x;
        __syncthreads();
    }
    int ex = (t > 0) ? sh[t - 1] : 0;
#pragma unroll
    for (int i = 0; i < 4; ++i) { int idx = t * 4 + i; if (idx < nb) { int vv = v[i]; bsum[idx] = ex; ex += vv; } }
}
__global__ void scan3_k(const int* __restrict__ cnt, const int* __restrict__ boff,
                        int* __restrict__ ptr, int* __restrict__ cursor, int n, int total) {
    __shared__ int sh[256];
    int t = threadIdx.x;
    int base = (blockIdx.x << 10) + (t << 2);
    int v[4]; int loc = 0;
#pragma unroll
    for (int i = 0; i < 4; ++i) { int idx = base + i; v[i] = (idx < n) ? cnt[idx] : 0; loc += v[i]; }
    sh[t] = loc; __syncthreads();
    for (int off = 1; off < 256; off <<= 1) {
        int x = (t >= off) ? sh[t - off] : 0;
        __syncthreads();
        sh[t] += x;
        __syncthreads();
    }
    int ex = boff[blockIdx.x] + ((t > 0) ? sh[t - 1] : 0);
#pragma unroll
    for (int i = 0; i < 4; ++i) {
        int idx = base + i;
        if (idx < n) { ptr[idx] = ex; cursor[idx] = ex; ex += v[i]; }
    }
    if (blockIdx.x == 0 && t == 0) ptr[n] = total;
}
__global__ void scatter_k(const int* __restrict__ src, const int* __restrict__ dst,
                          const int* __restrict__ et, int* __restrict__ cursor,
                          int* __restrict__ ssorted, int ne) {
    int e = blockIdx.x * 256 + threadIdx.x;
    if (e < ne) {
        int seg = dst[e] * RR + et[e];
        int pos = atomicAdd(&cursor[seg], 1);
        ssorted[pos] = src[e];
    }
}

// ---------------- weight / feature prep ----------------
// wfrag layout (per layer): [kb][frag=ks*8+nt][lane][j] bf16  — B-fragment-major so the
// layer kernel's per-(ks,nt) load is lane*16B contiguous (perfect coalescing, L2-resident).
// Element = W_t[o][i] with o = nt*16 + (lane&15), i = ks*32 + (lane>>4)*8 + j,
// where W_t[o][i] = rel_w[l][kb][i][o] (kb<7) or root_w[l][i][o] (kb==7).
__global__ void prep_w_k(const float* __restrict__ rel_w, const float* __restrict__ root_w,
                         unsigned short* __restrict__ wall) {
    int idx = blockIdx.x * 256 + threadIdx.x;
    if (idx >= 3 * 8 * 16384) return;
    int l = idx >> 17;
    int r2 = idx & 131071;
    int kb = r2 >> 14;
    int f = r2 & 16383;
    int frag = f >> 9;          // 0..31
    int ks = frag >> 3, nt = frag & 7;
    int q = f & 511;
    int lane = q >> 3, j = q & 7;
    int o = (nt << 4) + (lane & 15);
    int i = (ks << 5) + ((lane >> 4) << 3) + j;
    float v = (kb < RR) ? rel_w[(((l * RR + kb) << 7) + i) * 128 + o]
                        : root_w[((l << 7) + i) * 128 + o];
    wall[idx] = f2b(v);
}
__global__ void prep_h_k(const int* __restrict__ x, const float* __restrict__ embed,
                         unsigned short* __restrict__ h, int n) {
    int i = blockIdx.x * 256 + threadIdx.x;
    if (i >= n * 16) return;
    int node = i >> 4, c8 = (i & 15) << 3;
    const float* e = embed + ((size_t)x[node] << 7) + c8;
    float4 f0 = *(const float4*)e;
    float4 f1 = *(const float4*)(e + 4);
    uint4 o4;
    o4.x = (unsigned)f2b(f0.x) | ((unsigned)f2b(f0.y) << 16);
    o4.y = (unsigned)f2b(f0.z) | ((unsigned)f2b(f0.w) << 16);
    o4.z = (unsigned)f2b(f1.x) | ((unsigned)f2b(f1.y) << 16);
    o4.w = (unsigned)f2b(f1.z) | ((unsigned)f2b(f1.w) << 16);
    *(uint4*)(h + ((size_t)node << 7) + c8) = o4;
}

#define ACC8(base, v) { \
    av[base+0] += uhi2f((v).x << 16); av[base+1] += uhi2f((v).x & 0xffff0000u); \
    av[base+2] += uhi2f((v).y << 16); av[base+3] += uhi2f((v).y & 0xffff0000u); \
    av[base+4] += uhi2f((v).z << 16); av[base+5] += uhi2f((v).z & 0xffff0000u); \
    av[base+6] += uhi2f((v).w << 16); av[base+7] += uhi2f((v).w & 0xffff0000u); }

// ---------------- fused RGCN layer: register-resident aggregate -> MFMA ----------------
// No LDS, no barriers. Lane (wave,n16,quad) aggregates node=node0+wave*16+n16,
// cols {ks*32 + quad*8 + j} — exactly its own MFMA A-fragments for all 4 ks.
__global__ __launch_bounds__(256, 4) void layer_k(
    const unsigned short* __restrict__ h_in,   // bf16 [N][128]
    unsigned short* __restrict__ h_out,        // bf16 [N][128]
    const unsigned short* __restrict__ wfrag,  // bf16 [8][32][512] fragment-major
    const float* __restrict__ bias,
    const float* __restrict__ bn_g, const float* __restrict__ bn_b,
    const float* __restrict__ bn_m, const float* __restrict__ bn_v,
    const int* __restrict__ seg_ptr, const int* __restrict__ src_sorted,
    int nnodes, int bnrelu)
{
    const int tid  = threadIdx.x;
    const int wave = tid >> 6;
    const int lane = tid & 63;
    const int n16  = lane & 15;
    const int quad = lane >> 4;
    const int node0 = blockIdx.x << 6;
    const int gnode = node0 + (wave << 4) + n16;
    const bool valid = gnode < nnodes;

    int p[8];
    if (valid) {
        int b = gnode * RR;
#pragma unroll
        for (int i = 0; i < 8; ++i) p[i] = seg_ptr[b + i];
    }

    f32x4 acc[8];
#pragma unroll
    for (int i = 0; i < 8; ++i) acc[i] = (f32x4){0.f, 0.f, 0.f, 0.f};

    const unsigned short* wl = wfrag + (lane << 3);

    for (int kb = 0; kb < 8; ++kb) {
        float av[32];
#pragma unroll
        for (int i = 0; i < 32; ++i) av[i] = 0.f;
        float scale = 1.f;
        if (valid) {
            if (kb < RR) {
                int e0 = p[kb], e1 = p[kb + 1];
                int c = e1 - e0;
                if (c > 0) scale = __builtin_amdgcn_rcpf((float)c);
                int e = e0;
                for (; e + 2 <= e1; e += 2) {
                    int s0 = src_sorted[e];
                    int s1 = src_sorted[e + 1];
                    const unsigned short* h0 = h_in + ((size_t)s0 << 7) + (quad << 3);
                    const unsigned short* h1 = h_in + ((size_t)s1 << 7) + (quad << 3);
                    uint4 a0 = *(const uint4*)(h0);
                    uint4 a1 = *(const uint4*)(h0 + 32);
                    uint4 a2 = *(const uint4*)(h0 + 64);
                    uint4 a3 = *(const uint4*)(h0 + 96);
                    uint4 b0 = *(const uint4*)(h1);
                    uint4 b1 = *(const uint4*)(h1 + 32);
                    uint4 b2 = *(const uint4*)(h1 + 64);
                    uint4 b3 = *(const uint4*)(h1 + 96);
                    ACC8(0, a0); ACC8(8, a1); ACC8(16, a2); ACC8(24, a3);
                    ACC8(0, b0); ACC8(8, b1); ACC8(16, b2); ACC8(24, b3);
                }
                if (e < e1) {
                    int s0 = src_sorted[e];
                    const unsigned short* h0 = h_in + ((size_t)s0 << 7) + (quad << 3);
                    uint4 a0 = *(const uint4*)(h0);
                    uint4 a1 = *(const uint4*)(h0 + 32);
                    uint4 a2 = *(const uint4*)(h0 + 64);
                    uint4 a3 = *(const uint4*)(h0 + 96);
                    ACC8(0, a0); ACC8(8, a1); ACC8(16, a2); ACC8(24, a3);
                }
            } else {  // root: own row
                const unsigned short* h0 = h_in + ((size_t)gnode << 7) + (quad << 3);
                uint4 a0 = *(const uint4*)(h0);
                uint4 a1 = *(const uint4*)(h0 + 32);
                uint4 a2 = *(const uint4*)(h0 + 64);
                uint4 a3 = *(const uint4*)(h0 + 96);
                ACC8(0, a0); ACC8(8, a1); ACC8(16, a2); ACC8(24, a3);
            }
        }
        bf16x8 afr[4];
        unsigned short* ap = (unsigned short*)afr;
#pragma unroll
        for (int i = 0; i < 32; ++i) ap[i] = f2b(av[i] * scale);

        const unsigned short* wk = wl + (kb << 14);
#pragma unroll
        for (int ks = 0; ks < 4; ++ks) {
#pragma unroll
            for (int nt = 0; nt < 8; ++nt) {
                bf16x8 bfr = *(const bf16x8*)(wk + (((ks << 3) + nt) << 9));
                acc[nt] = __builtin_amdgcn_mfma_f32_16x16x32_bf16(afr[ks], bfr, acc[nt], 0, 0, 0);
            }
        }
    }

    // epilogue: +bias, BN, ReLU (layers 0/1), store bf16
    // C/D layout: col = lane&15, row = (lane>>4)*4 + reg
#pragma unroll
    for (int nt = 0; nt < 8; ++nt) {
        int j = (nt << 4) + n16;
        float bj = bias[j];
        float sc = 1.f, sh = 0.f;
        if (bnrelu) {
            sc = bn_g[j] * rsqrtf(bn_v[j] + EPSBN);
            sh = bn_b[j] - bn_m[j] * sc;
        }
#pragma unroll
        for (int r = 0; r < 4; ++r) {
            int node = node0 + (wave << 4) + (quad << 2) + r;
            if (node < nnodes) {
                float v = acc[nt][r] + bj;
                if (bnrelu) v = fmaxf(v * sc + sh, 0.f);
                h_out[((size_t)node << 7) + j] = f2b(v);
            }
        }
    }
}

// ---------------- MLP head: 16 rows/block, fully in-LDS ----------------
__global__ __launch_bounds__(256) void mlp_k(
    const unsigned short* __restrict__ hfin,
    const int* __restrict__ home, const int* __restrict__ away,
    const float* __restrict__ w0, const float* __restrict__ bb0,
    const float* __restrict__ w1, const float* __restrict__ bb1,
    const float* __restrict__ w2, const float* __restrict__ bb2,
    float* __restrict__ out, int Bn)
{
    __shared__ __attribute__((aligned(16))) float g0[16][256];
    __shared__ __attribute__((aligned(16))) float g1[16][256];
    __shared__ float lg[16][4];
    int t = threadIdx.x;
    {
        int row = t >> 4;
        int cseg = (t & 15) << 4;
        int gr = (blockIdx.x << 4) + row;
        int gc = (gr < Bn) ? gr : 0;
        int hn = home[gc], an = away[gc];
        const unsigned short* sp = (cseg < 128) ? (hfin + ((size_t)hn << 7) + cseg)
                                                : (hfin + ((size_t)an << 7) + (cseg - 128));
#pragma unroll
        for (int c8 = 0; c8 < 2; ++c8) {
            uint4 v = *(const uint4*)(sp + (c8 << 3));
            int base = cseg + (c8 << 3);
            g0[row][base+0] = uhi2f(v.x << 16); g0[row][base+1] = uhi2f(v.x & 0xffff0000u);
            g0[row][base+2] = uhi2f(v.y << 16); g0[row][base+3] = uhi2f(v.y & 0xffff0000u);
            g0[row][base+4] = uhi2f(v.z << 16); g0[row][base+5] = uhi2f(v.z & 0xffff0000u);
            g0[row][base+6] = uhi2f(v.w << 16); g0[row][base+7] = uhi2f(v.w & 0xffff0000u);
        }
    }
    __syncthreads();
    {   // fc0
        float acc[16];
#pragma unroll
        for (int r = 0; r < 16; ++r) acc[r] = 0.f;
        const float* wr = w0 + (t << 8);
        for (int i = 0; i < 256; i += 4) {
            float4 w = *(const float4*)(wr + i);
#pragma unroll
            for (int r = 0; r < 16; ++r) {
                float4 g = *(const float4*)&g0[r][i];
                acc[r] += w.x * g.x + w.y * g.y + w.z * g.z + w.w * g.w;
            }
        }
        float bb = bb0[t];
#pragma unroll
        for (int r = 0; r < 16; ++r) g1[r][t] = fmaxf(acc[r] + bb, 0.f);
    }
    __syncthreads();
    {   // fc1
        int o = t & 127, rg = t >> 7;
        float acc[8];
#pragma unroll
        for (int r = 0; r < 8; ++r) acc[r] = 0.f;
        const float* wr = w1 + (o << 8);
        for (int i = 0; i < 256; i += 4) {
            float4 w = *(const float4*)(wr + i);
#pragma unroll
            for (int r = 0; r < 8; ++r) {
                float4 g = *(const float4*)&g1[(rg << 3) + r][i];
                acc[r] += w.x * g.x + w.y * g.y + w.z * g.z + w.w * g.w;
            }
        }
        float bb = bb1[o];
#pragma unroll
        for (int r = 0; r < 8; ++r) g0[(rg << 3) + r][o] = fmaxf(acc[r] + bb, 0.f);
    }
    __syncthreads();
    if (t < 48) {   // fc2
        int row = t / 3, cls = t - row * 3;
        const float* wr = w2 + (cls << 7);
        float a = 0.f;
        for (int i = 0; i < 128; i += 4) {
            float4 w = *(const float4*)(wr + i);
            float4 g = *(const float4*)&g0[row][i];
            a += w.x * g.x + w.y * g.y + w.z * g.z + w.w * g.w;
        }
        lg[row][cls] = a + bb2[cls];
    }
    __syncthreads();
    if (t < 16) {   // log_softmax + store
        int gr = (blockIdx.x << 4) + t;
        if (gr < Bn) {
            float l0 = lg[t][0], l1 = lg[t][1], l2 = lg[t][2];
            float m = fmaxf(l0, fmaxf(l1, l2));
            float lse = m + logf(expf(l0 - m) + expf(l1 - m) + expf(l2 - m));
            out[gr * 3 + 0] = l0 - lse;
            out[gr * 3 + 1] = l1 - lse;
            out[gr * 3 + 2] = l2 - lse;
        }
    }
}

extern "C" void kernel_launch(void* const* d_in, const int* in_sizes, int n_in,
                              void* d_out, int out_size, void* d_ws, size_t ws_size,
                              hipStream_t stream) {
    const int*   x      = (const int*)d_in[0];
    const int*   eidx   = (const int*)d_in[1];   // [2, E]
    const int*   etype  = (const int*)d_in[2];
    const int*   home   = (const int*)d_in[3];
    const int*   away   = (const int*)d_in[4];
    const float* embed  = (const float*)d_in[5];
    const float* rel_w  = (const float*)d_in[6];
    const float* root_w = (const float*)d_in[7];
    const float* conv_b = (const float*)d_in[8];
    const float* bn_g   = (const float*)d_in[9];
    const float* bn_b   = (const float*)d_in[10];
    const float* bn_m   = (const float*)d_in[11];
    const float* bn_v   = (const float*)d_in[12];
    const float* fc0w   = (const float*)d_in[13];
    const float* fc0b   = (const float*)d_in[14];
    const float* fc1w   = (const float*)d_in[15];
    const float* fc1b   = (const float*)d_in[16];
    const float* fc2w   = (const float*)d_in[17];
    const float* fc2b   = (const float*)d_in[18];
    float* out = (float*)d_out;

    const int N_ = in_sizes[0];
    const int E_ = in_sizes[2];
    const int B_ = in_sizes[3];
    const int NS = N_ * RR;

    char* ws = (char*)d_ws;
    auto alloc = [&](size_t bytes) -> char* {
        char* p = ws;
        ws += (bytes + 255) & ~(size_t)255;
        return p;
    };
    int* ptr         = (int*)alloc((size_t)(NS + 1) * 4);
    int* cursor      = (int*)alloc((size_t)NS * 4);
    int* bsum        = (int*)alloc(4096);
    int* src_sorted  = (int*)alloc((size_t)E_ * 4);
    unsigned short* wall = (unsigned short*)alloc((size_t)3 * 8 * 16384 * 2);
    unsigned short* hA   = (unsigned short*)alloc((size_t)N_ * 128 * 2);
    unsigned short* hB   = (unsigned short*)alloc((size_t)N_ * 128 * 2);

    const int nb = (NS + 1023) / 1024;

    // CSR build (segments constant across layers)
    zero_i32_k<<<(NS + 255) / 256, 256, 0, stream>>>(cursor, NS);
    hist_k<<<(E_ + 255) / 256, 256, 0, stream>>>(eidx + E_, etype, cursor, E_);
    scan1_k<<<nb, 256, 0, stream>>>(cursor, bsum, NS);
    scan2_k<<<1, 256, 0, stream>>>(bsum, nb);
    scan3_k<<<nb, 256, 0, stream>>>(cursor, bsum, ptr, cursor, NS, E_);
    scatter_k<<<(E_ + 255) / 256, 256, 0, stream>>>(eidx, eidx + E_, etype, cursor, src_sorted, E_);

    // weight + feature prep
    prep_w_k<<<(3 * 8 * 16384 + 255) / 256, 256, 0, stream>>>(rel_w, root_w, wall);
    prep_h_k<<<(N_ * 16 + 255) / 256, 256, 0, stream>>>(x, embed, hA, N_);

    const int lgrid = (N_ + 63) / 64;
    layer_k<<<lgrid, 256, 0, stream>>>(hA, hB, wall + 0 * 8 * 16384, conv_b + 0,
                                       bn_g + 0, bn_b + 0, bn_m + 0, bn_v + 0,
                                       ptr, src_sorted, N_, 1);
    layer_k<<<lgrid, 256, 0, stream>>>(hB, hA, wall + 1 * 8 * 16384, conv_b + 128,
                                       bn_g + 128, bn_b + 128, bn_m + 128, bn_v + 128,
                                       ptr, src_sorted, N_, 1);
    layer_k<<<lgrid, 256, 0, stream>>>(hA, hB, wall + 2 * 8 * 16384, conv_b + 256,
                                       bn_g, bn_b, bn_m, bn_v,
                                       ptr, src_sorted, N_, 0);

    mlp_k<<<(B_ + 15) / 16, 256, 0, stream>>>(hB, home, away, fc0w, fc0b, fc1w, fc1b,
                                              fc2w, fc2b, out, B_);
}

// Round 4
// 795.162 us; speedup vs baseline: 1.2352x; 1.2352x over previous
//
#include <hip/hip_runtime.h>
#include <hip/hip_bf16.h>

#define RR 7
#define EPSBN 1e-5f

typedef __attribute__((ext_vector_type(8))) __bf16 bf16x8;
typedef __attribute__((ext_vector_type(4))) float f32x4;
typedef __attribute__((ext_vector_type(2))) float f32x2;

__device__ __forceinline__ float uhi2f(unsigned int u) {
    union { unsigned int i; float f; } c; c.i = u; return c.f;
}
__device__ __forceinline__ unsigned short f2b(float f) {
    union { float f; unsigned int i; } c; c.f = f;
    unsigned int x = c.i;
    return (unsigned short)((x + 0x7fffu + ((x >> 16) & 1u)) >> 16);
}

// ---------------- CSR build ----------------
__global__ void hist_k(const int* __restrict__ dst, const int* __restrict__ et,
                       int* __restrict__ cnt, int ne) {
    int e = blockIdx.x * 256 + threadIdx.x;
    if (e < ne) atomicAdd(&cnt[dst[e] * RR + et[e]], 1);
}
__global__ void scan1_k(const int* __restrict__ cnt, int* __restrict__ bsum, int n) {
    __shared__ int sh[256];
    int base = blockIdx.x << 10;
    int s = 0;
    for (int i = threadIdx.x; i < 1024; i += 256) { int idx = base + i; if (idx < n) s += cnt[idx]; }
    sh[threadIdx.x] = s; __syncthreads();
    for (int off = 128; off > 0; off >>= 1) {
        if (threadIdx.x < off) sh[threadIdx.x] += sh[threadIdx.x + off];
        __syncthreads();
    }
    if (threadIdx.x == 0) bsum[blockIdx.x] = sh[0];
}
__global__ void scan2_k(int* __restrict__ bsum, int nb) {   // nb <= 1024
    __shared__ int sh[256];
    int t = threadIdx.x;
    int v[4]; int loc = 0;
#pragma unroll
    for (int i = 0; i < 4; ++i) { int idx = t * 4 + i; v[i] = (idx < nb) ? bsum[idx] : 0; loc += v[i]; }
    sh[t] = loc; __syncthreads();
    for (int off = 1; off < 256; off <<= 1) {
        int x = (t >= off) ? sh[t - off] : 0;
        __syncthreads();
        sh[t] += x;
        __syncthreads();
    }
    int ex = (t > 0) ? sh[t - 1] : 0;
#pragma unroll
    for (int i = 0; i < 4; ++i) { int idx = t * 4 + i; if (idx < nb) { int vv = v[i]; bsum[idx] = ex; ex += vv; } }
}
__global__ void scan3_k(const int* __restrict__ cnt, const int* __restrict__ boff,
                        int* __restrict__ ptr, int* __restrict__ cursor, int n, int total) {
    __shared__ int sh[256];
    int t = threadIdx.x;
    int base = (blockIdx.x << 10) + (t << 2);
    int v[4]; int loc = 0;
#pragma unroll
    for (int i = 0; i < 4; ++i) { int idx = base + i; v[i] = (idx < n) ? cnt[idx] : 0; loc += v[i]; }
    sh[t] = loc; __syncthreads();
    for (int off = 1; off < 256; off <<= 1) {
        int x = (t >= off) ? sh[t - off] : 0;
        __syncthreads();
        sh[t] += x;
        __syncthreads();
    }
    int ex = boff[blockIdx.x] + ((t > 0) ? sh[t - 1] : 0);
#pragma unroll
    for (int i = 0; i < 4; ++i) {
        int idx = base + i;
        if (idx < n) { ptr[idx] = ex; cursor[idx] = ex; ex += v[i]; }
    }
    if (blockIdx.x == 0 && t == 0) ptr[n] = total;
}
__global__ void scatter_k(const int* __restrict__ src, const int* __restrict__ dst,
                          const int* __restrict__ et, int* __restrict__ cursor,
                          int* __restrict__ ssorted, int ne) {
    int e = blockIdx.x * 256 + threadIdx.x;
    if (e < ne) {
        int seg = dst[e] * RR + et[e];
        int pos = atomicAdd(&cursor[seg], 1);
        ssorted[pos] = src[e];
    }
}

// ---------------- weight / feature prep ----------------
// wall layout (per layer): [kb][frag=ks*8+nt][lane][j] bf16 — fragment-major.
// Element = W_t[o][i], o = nt*16 + (lane&15), i = ks*32 + (lane>>4)*8 + j,
// W_t[o][i] = rel_w[l][kb][i][o] (kb<7) or root_w[l][i][o] (kb==7).
__global__ void prep_w_k(const float* __restrict__ rel_w, const float* __restrict__ root_w,
                         unsigned short* __restrict__ wall) {
    int idx = blockIdx.x * 256 + threadIdx.x;
    if (idx >= 3 * 8 * 16384) return;
    int l = idx >> 17;
    int r2 = idx & 131071;
    int kb = r2 >> 14;
    int f = r2 & 16383;
    int frag = f >> 9;          // 0..31
    int ks = frag >> 3, nt = frag & 7;
    int q = f & 511;
    int lane = q >> 3, j = q & 7;
    int o = (nt << 4) + (lane & 15);
    int i = (ks << 5) + ((lane >> 4) << 3) + j;
    float v = (kb < RR) ? rel_w[(((l * RR + kb) << 7) + i) * 128 + o]
                        : root_w[((l << 7) + i) * 128 + o];
    wall[idx] = f2b(v);
}
__global__ void prep_h_k(const int* __restrict__ x, const float* __restrict__ embed,
                         unsigned short* __restrict__ h, int n) {
    int i = blockIdx.x * 256 + threadIdx.x;
    if (i >= n * 16) return;
    int node = i >> 4, c8 = (i & 15) << 3;
    const float* e = embed + ((size_t)x[node] << 7) + c8;
    float4 f0 = *(const float4*)e;
    float4 f1 = *(const float4*)(e + 4);
    uint4 o4;
    o4.x = (unsigned)f2b(f0.x) | ((unsigned)f2b(f0.y) << 16);
    o4.y = (unsigned)f2b(f0.z) | ((unsigned)f2b(f0.w) << 16);
    o4.z = (unsigned)f2b(f1.x) | ((unsigned)f2b(f1.y) << 16);
    o4.w = (unsigned)f2b(f1.z) | ((unsigned)f2b(f1.w) << 16);
    *(uint4*)(h + ((size_t)node << 7) + c8) = o4;
}

#define PAIRF(w) ((f32x2){uhi2f((w) << 16), uhi2f((w) & 0xffff0000u)})
#define ACCP(b, u) { av2[(b)+0] += PAIRF((u).x); av2[(b)+1] += PAIRF((u).y); \
                     av2[(b)+2] += PAIRF((u).z); av2[(b)+3] += PAIRF((u).w); }

// ---------------- fused RGCN layer ----------------
// A-fragments aggregated in registers (pk_add f32x2); W staged per-kb in LDS
// (fragment-major -> linear copy, conflict-free ds_read_b128).
__global__ __launch_bounds__(256, 4) void layer_k(
    const unsigned short* __restrict__ h_in,   // bf16 [N][128]
    unsigned short* __restrict__ h_out,        // bf16 [N][128]
    const unsigned short* __restrict__ wfrag,  // bf16 [8][32][512] fragment-major
    const float* __restrict__ bias,
    const float* __restrict__ bn_g, const float* __restrict__ bn_b,
    const float* __restrict__ bn_m, const float* __restrict__ bn_v,
    const int* __restrict__ seg_ptr, const int* __restrict__ src_sorted,
    int nnodes, int bnrelu)
{
    __shared__ __attribute__((aligned(16))) unsigned short Wt[16384];  // 32 KB

    const int tid  = threadIdx.x;
    const int wave = tid >> 6;
    const int lane = tid & 63;
    const int n16  = lane & 15;
    const int quad = lane >> 4;
    const int node0 = blockIdx.x << 6;
    const int gnode = node0 + (wave << 4) + n16;
    const bool valid = gnode < nnodes;
    const int segbase = gnode * RR;

    f32x4 acc[8];
#pragma unroll
    for (int i = 0; i < 8; ++i) acc[i] = (f32x4){0.f, 0.f, 0.f, 0.f};

    int ecur = valid ? seg_ptr[segbase] : 0;   // rolling e0: ptr[segbase+kb]

    for (int kb = 0; kb < 8; ++kb) {
        // ---- gather (register-resident, no barriers) ----
        f32x2 av2[16];
#pragma unroll
        for (int i = 0; i < 16; ++i) av2[i] = (f32x2){0.f, 0.f};
        float scale = 1.f;
        if (valid) {
            int e0, e1;
            if (kb < RR) {
                e0 = ecur;
                e1 = seg_ptr[segbase + kb + 1];
                ecur = e1;
                int c = e1 - e0;
                if (c > 0) scale = __builtin_amdgcn_rcpf((float)c);
            } else { e0 = 0; e1 = 1; }
            for (int e = e0; e < e1; ++e) {
                int s = (kb < RR) ? src_sorted[e] : gnode;
                const unsigned short* hp = h_in + ((size_t)s << 7) + (quad << 3);
                uint4 u0 = *(const uint4*)(hp);
                uint4 u1 = *(const uint4*)(hp + 32);
                uint4 u2 = *(const uint4*)(hp + 64);
                uint4 u3 = *(const uint4*)(hp + 96);
                ACCP(0, u0); ACCP(4, u1); ACCP(8, u2); ACCP(12, u3);
            }
        }
        // ---- stage W_kb into LDS (linear, coalesced) ----
        __syncthreads();   // previous kb's MFMA done before overwrite
        {
            const uint4* ws4 = (const uint4*)(wfrag + ((size_t)kb << 14));
            uint4* wt4 = (uint4*)Wt;
#pragma unroll
            for (int c = tid; c < 2048; c += 256) wt4[c] = ws4[c];
        }
        __syncthreads();
        // ---- convert A to bf16 fragments (HW packed cvt) ----
        uint4 au[4];
#pragma unroll
        for (int ks = 0; ks < 4; ++ks) {
            unsigned pw[4];
#pragma unroll
            for (int m = 0; m < 4; ++m) {
                f32x2 q = av2[(ks << 2) + m] * scale;
                __hip_bfloat162 b2 = __float22bfloat162_rn(make_float2(q.x, q.y));
                unsigned u; __builtin_memcpy(&u, &b2, 4);
                pw[m] = u;
            }
            au[ks].x = pw[0]; au[ks].y = pw[1]; au[ks].z = pw[2]; au[ks].w = pw[3];
        }
        // ---- MFMA ----
#pragma unroll
        for (int ks = 0; ks < 4; ++ks) {
            bf16x8 af;
            __builtin_memcpy(&af, &au[ks], 16);
#pragma unroll
            for (int nt = 0; nt < 8; ++nt) {
                bf16x8 bfr = *(const bf16x8*)&Wt[(((ks << 3) + nt) << 9) + (lane << 3)];
                acc[nt] = __builtin_amdgcn_mfma_f32_16x16x32_bf16(af, bfr, acc[nt], 0, 0, 0);
            }
        }
    }

    // epilogue: +bias, BN, ReLU (layers 0/1), store bf16
    // C/D layout: col = lane&15, row = (lane>>4)*4 + reg
#pragma unroll
    for (int nt = 0; nt < 8; ++nt) {
        int j = (nt << 4) + n16;
        float bj = bias[j];
        float sc = 1.f, sh = 0.f;
        if (bnrelu) {
            sc = bn_g[j] * rsqrtf(bn_v[j] + EPSBN);
            sh = bn_b[j] - bn_m[j] * sc;
        }
#pragma unroll
        for (int r = 0; r < 4; ++r) {
            int node = node0 + (wave << 4) + (quad << 2) + r;
            if (node < nnodes) {
                float v = acc[nt][r] + bj;
                if (bnrelu) v = fmaxf(v * sc + sh, 0.f);
                h_out[((size_t)node << 7) + j] = f2b(v);
            }
        }
    }
}

// ---------------- MLP head: 16 rows/block, fully in-LDS ----------------
__global__ __launch_bounds__(256) void mlp_k(
    const unsigned short* __restrict__ hfin,
    const int* __restrict__ home, const int* __restrict__ away,
    const float* __restrict__ w0, const float* __restrict__ bb0,
    const float* __restrict__ w1, const float* __restrict__ bb1,
    const float* __restrict__ w2, const float* __restrict__ bb2,
    float* __restrict__ out, int Bn)
{
    __shared__ __attribute__((aligned(16))) float g0[16][256];
    __shared__ __attribute__((aligned(16))) float g1[16][256];
    __shared__ float lg[16][4];
    int t = threadIdx.x;
    {
        int row = t >> 4;
        int cseg = (t & 15) << 4;
        int gr = (blockIdx.x << 4) + row;
        int gc = (gr < Bn) ? gr : 0;
        int hn = home[gc], an = away[gc];
        const unsigned short* sp = (cseg < 128) ? (hfin + ((size_t)hn << 7) + cseg)
                                                : (hfin + ((size_t)an << 7) + (cseg - 128));
#pragma unroll
        for (int c8 = 0; c8 < 2; ++c8) {
            uint4 v = *(const uint4*)(sp + (c8 << 3));
            int base = cseg + (c8 << 3);
            g0[row][base+0] = uhi2f(v.x << 16); g0[row][base+1] = uhi2f(v.x & 0xffff0000u);
            g0[row][base+2] = uhi2f(v.y << 16); g0[row][base+3] = uhi2f(v.y & 0xffff0000u);
            g0[row][base+4] = uhi2f(v.z << 16); g0[row][base+5] = uhi2f(v.z & 0xffff0000u);
            g0[row][base+6] = uhi2f(v.w << 16); g0[row][base+7] = uhi2f(v.w & 0xffff0000u);
        }
    }
    __syncthreads();
    {   // fc0
        float acc[16];
#pragma unroll
        for (int r = 0; r < 16; ++r) acc[r] = 0.f;
        const float* wr = w0 + (t << 8);
        for (int i = 0; i < 256; i += 4) {
            float4 w = *(const float4*)(wr + i);
#pragma unroll
            for (int r = 0; r < 16; ++r) {
                float4 g = *(const float4*)&g0[r][i];
                acc[r] += w.x * g.x + w.y * g.y + w.z * g.z + w.w * g.w;
            }
        }
        float bb = bb0[t];
#pragma unroll
        for (int r = 0; r < 16; ++r) g1[r][t] = fmaxf(acc[r] + bb, 0.f);
    }
    __syncthreads();
    {   // fc1
        int o = t & 127, rg = t >> 7;
        float acc[8];
#pragma unroll
        for (int r = 0; r < 8; ++r) acc[r] = 0.f;
        const float* wr = w1 + (o << 8);
        for (int i = 0; i < 256; i += 4) {
            float4 w = *(const float4*)(wr + i);
#pragma unroll
            for (int r = 0; r < 8; ++r) {
                float4 g = *(const float4*)&g1[(rg << 3) + r][i];
                acc[r] += w.x * g.x + w.y * g.y + w.z * g.z + w.w * g.w;
            }
        }
        float bb = bb1[o];
#pragma unroll
        for (int r = 0; r < 8; ++r) g0[(rg << 3) + r][o] = fmaxf(acc[r] + bb, 0.f);
    }
    __syncthreads();
    if (t < 48) {   // fc2
        int row = t / 3, cls = t - row * 3;
        const float* wr = w2 + (cls << 7);
        float a = 0.f;
        for (int i = 0; i < 128; i += 4) {
            float4 w = *(const float4*)(wr + i);
            float4 g = *(const float4*)&g0[row][i];
            a += w.x * g.x + w.y * g.y + w.z * g.z + w.w * g.w;
        }
        lg[row][cls] = a + bb2[cls];
    }
    __syncthreads();
    if (t < 16) {   // log_softmax + store
        int gr = (blockIdx.x << 4) + t;
        if (gr < Bn) {
            float l0 = lg[t][0], l1 = lg[t][1], l2 = lg[t][2];
            float m = fmaxf(l0, fmaxf(l1, l2));
            float lse = m + logf(expf(l0 - m) + expf(l1 - m) + expf(l2 - m));
            out[gr * 3 + 0] = l0 - lse;
            out[gr * 3 + 1] = l1 - lse;
            out[gr * 3 + 2] = l2 - lse;
        }
    }
}

extern "C" void kernel_launch(void* const* d_in, const int* in_sizes, int n_in,
                              void* d_out, int out_size, void* d_ws, size_t ws_size,
                              hipStream_t stream) {
    const int*   x      = (const int*)d_in[0];
    const int*   eidx   = (const int*)d_in[1];   // [2, E]
    const int*   etype  = (const int*)d_in[2];
    const int*   home   = (const int*)d_in[3];
    const int*   away   = (const int*)d_in[4];
    const float* embed  = (const float*)d_in[5];
    const float* rel_w  = (const float*)d_in[6];
    const float* root_w = (const float*)d_in[7];
    const float* conv_b = (const float*)d_in[8];
    const float* bn_g   = (const float*)d_in[9];
    const float* bn_b   = (const float*)d_in[10];
    const float* bn_m   = (const float*)d_in[11];
    const float* bn_v   = (const float*)d_in[12];
    const float* fc0w   = (const float*)d_in[13];
    const float* fc0b   = (const float*)d_in[14];
    const float* fc1w   = (const float*)d_in[15];
    const float* fc1b   = (const float*)d_in[16];
    const float* fc2w   = (const float*)d_in[17];
    const float* fc2b   = (const float*)d_in[18];
    float* out = (float*)d_out;

    const int N_ = in_sizes[0];
    const int E_ = in_sizes[2];
    const int B_ = in_sizes[3];
    const int NS = N_ * RR;

    char* ws = (char*)d_ws;
    auto alloc = [&](size_t bytes) -> char* {
        char* p = ws;
        ws += (bytes + 255) & ~(size_t)255;
        return p;
    };
    int* ptr         = (int*)alloc((size_t)(NS + 1) * 4);
    int* cursor      = (int*)alloc((size_t)NS * 4);
    int* bsum        = (int*)alloc(4096);
    int* src_sorted  = (int*)alloc((size_t)E_ * 4);
    unsigned short* wall = (unsigned short*)alloc((size_t)3 * 8 * 16384 * 2);
    unsigned short* hA   = (unsigned short*)alloc((size_t)N_ * 128 * 2);
    unsigned short* hB   = (unsigned short*)alloc((size_t)N_ * 128 * 2);

    const int nb = (NS + 1023) / 1024;

    // CSR build (segments constant across layers)
    (void)hipMemsetAsync(cursor, 0, (size_t)NS * 4, stream);
    hist_k<<<(E_ + 255) / 256, 256, 0, stream>>>(eidx + E_, etype, cursor, E_);
    scan1_k<<<nb, 256, 0, stream>>>(cursor, bsum, NS);
    scan2_k<<<1, 256, 0, stream>>>(bsum, nb);
    scan3_k<<<nb, 256, 0, stream>>>(cursor, bsum, ptr, cursor, NS, E_);
    scatter_k<<<(E_ + 255) / 256, 256, 0, stream>>>(eidx, eidx + E_, etype, cursor, src_sorted, E_);

    // weight + feature prep
    prep_w_k<<<(3 * 8 * 16384 + 255) / 256, 256, 0, stream>>>(rel_w, root_w, wall);
    prep_h_k<<<(N_ * 16 + 255) / 256, 256, 0, stream>>>(x, embed, hA, N_);

    const int lgrid = (N_ + 63) / 64;
    layer_k<<<lgrid, 256, 0, stream>>>(hA, hB, wall + 0 * 8 * 16384, conv_b + 0,
                                       bn_g + 0, bn_b + 0, bn_m + 0, bn_v + 0,
                                       ptr, src_sorted, N_, 1);
    layer_k<<<lgrid, 256, 0, stream>>>(hB, hA, wall + 1 * 8 * 16384, conv_b + 128,
                                       bn_g + 128, bn_b + 128, bn_m + 128, bn_v + 128,
                                       ptr, src_sorted, N_, 1);
    layer_k<<<lgrid, 256, 0, stream>>>(hA, hB, wall + 2 * 8 * 16384, conv_b + 256,
                                       bn_g, bn_b, bn_m, bn_v,
                                       ptr, src_sorted, N_, 0);

    mlp_k<<<(B_ + 15) / 16, 256, 0, stream>>>(hB, home, away, fc0w, fc0b, fc1w, fc1b,
                                              fc2w, fc2b, out, B_);
}

// Round 5
// 671.925 us; speedup vs baseline: 1.4617x; 1.1834x over previous
//
#include <hip/hip_runtime.h>
#include <hip/hip_bf16.h>

#define RR 7
#define EPSBN 1e-5f

typedef __attribute__((ext_vector_type(8))) __bf16 bf16x8;
typedef __attribute__((ext_vector_type(4))) float f32x4;
typedef __attribute__((ext_vector_type(2))) float f32x2;

__device__ __forceinline__ float uhi2f(unsigned int u) {
    union { unsigned int i; float f; } c; c.i = u; return c.f;
}
__device__ __forceinline__ unsigned short f2b(float f) {
    union { float f; unsigned int i; } c; c.f = f;
    unsigned int x = c.i;
    return (unsigned short)((x + 0x7fffu + ((x >> 16) & 1u)) >> 16);
}

// ---------------- CSR build ----------------
__global__ void hist_k(const int* __restrict__ dst, const int* __restrict__ et,
                       int* __restrict__ cnt, int ne) {
    int e = blockIdx.x * 256 + threadIdx.x;
    if (e < ne) atomicAdd(&cnt[dst[e] * RR + et[e]], 1);
}
__global__ void scan1_k(const int* __restrict__ cnt, int* __restrict__ bsum, int n) {
    __shared__ int sh[256];
    int base = blockIdx.x << 10;
    int s = 0;
    for (int i = threadIdx.x; i < 1024; i += 256) { int idx = base + i; if (idx < n) s += cnt[idx]; }
    sh[threadIdx.x] = s; __syncthreads();
    for (int off = 128; off > 0; off >>= 1) {
        if (threadIdx.x < off) sh[threadIdx.x] += sh[threadIdx.x + off];
        __syncthreads();
    }
    if (threadIdx.x == 0) bsum[blockIdx.x] = sh[0];
}
__global__ void scan2_k(int* __restrict__ bsum, int nb) {   // nb <= 1024
    __shared__ int sh[256];
    int t = threadIdx.x;
    int v[4]; int loc = 0;
#pragma unroll
    for (int i = 0; i < 4; ++i) { int idx = t * 4 + i; v[i] = (idx < nb) ? bsum[idx] : 0; loc += v[i]; }
    sh[t] = loc; __syncthreads();
    for (int off = 1; off < 256; off <<= 1) {
        int x = (t >= off) ? sh[t - off] : 0;
        __syncthreads();
        sh[t] += x;
        __syncthreads();
    }
    int ex = (t > 0) ? sh[t - 1] : 0;
#pragma unroll
    for (int i = 0; i < 4; ++i) { int idx = t * 4 + i; if (idx < nb) { int vv = v[i]; bsum[idx] = ex; ex += vv; } }
}
__global__ void scan3_k(const int* __restrict__ cnt, const int* __restrict__ boff,
                        int* __restrict__ ptr, int* __restrict__ cursor, int n, int total) {
    __shared__ int sh[256];
    int t = threadIdx.x;
    int base = (blockIdx.x << 10) + (t << 2);
    int v[4]; int loc = 0;
#pragma unroll
    for (int i = 0; i < 4; ++i) { int idx = base + i; v[i] = (idx < n) ? cnt[idx] : 0; loc += v[i]; }
    sh[t] = loc; __syncthreads();
    for (int off = 1; off < 256; off <<= 1) {
        int x = (t >= off) ? sh[t - off] : 0;
        __syncthreads();
        sh[t] += x;
        __syncthreads();
    }
    int ex = boff[blockIdx.x] + ((t > 0) ? sh[t - 1] : 0);
#pragma unroll
    for (int i = 0; i < 4; ++i) {
        int idx = base + i;
        if (idx < n) { ptr[idx] = ex; cursor[idx] = ex; ex += v[i]; }
    }
    if (blockIdx.x == 0 && t == 0) ptr[n] = total;
}
__global__ void scatter_k(const int* __restrict__ src, const int* __restrict__ dst,
                          const int* __restrict__ et, int* __restrict__ cursor,
                          int* __restrict__ ssorted, int ne) {
    int e = blockIdx.x * 256 + threadIdx.x;
    if (e < ne) {
        int seg = dst[e] * RR + et[e];
        int pos = atomicAdd(&cursor[seg], 1);
        ssorted[pos] = src[e];
    }
}

// ---------------- weight / feature / BN prep ----------------
// wall layout: [l*8+kb][frag=ks*8+nt][lane][j] bf16 — fragment-major.
// Element = W_t[o][i] = W[i][o], o = nt*16+(lane&15), i = ks*32+((lane>>4)<<3)+j.
// One block per (l,kb): coalesced load -> LDS transpose -> coalesced frag write.
__global__ __launch_bounds__(256) void prep_w_k(const float* __restrict__ rel_w,
                                                const float* __restrict__ root_w,
                                                unsigned short* __restrict__ wall) {
    __shared__ unsigned short T[128][130];
    int l = blockIdx.x >> 3, kb = blockIdx.x & 7;
    const float* src = (kb < RR) ? rel_w + ((size_t)(l * RR + kb) << 14)
                                 : root_w + ((size_t)l << 14);
    int t = threadIdx.x;
    for (int c = t; c < 4096; c += 256) {
        float4 f = *(const float4*)(src + (c << 2));
        int i = c >> 5, o = (c & 31) << 2;
        T[i][o] = f2b(f.x); T[i][o+1] = f2b(f.y); T[i][o+2] = f2b(f.z); T[i][o+3] = f2b(f.w);
    }
    __syncthreads();
    unsigned short* dst = wall + ((size_t)blockIdx.x << 14);
    for (int c = t; c < 2048; c += 256) {
        int frag = c >> 6;             // ks*8+nt
        int lane = c & 63;
        int ks = frag >> 3, nt = frag & 7;
        int o = (nt << 4) + (lane & 15);
        int ib = (ks << 5) + ((lane >> 4) << 3);
        uint4 o4;
        o4.x = (unsigned)T[ib+0][o] | ((unsigned)T[ib+1][o] << 16);
        o4.y = (unsigned)T[ib+2][o] | ((unsigned)T[ib+3][o] << 16);
        o4.z = (unsigned)T[ib+4][o] | ((unsigned)T[ib+5][o] << 16);
        o4.w = (unsigned)T[ib+6][o] | ((unsigned)T[ib+7][o] << 16);
        *(uint4*)(dst + (c << 3)) = o4;
    }
}
__global__ void prep_h_k(const int* __restrict__ x, const float* __restrict__ embed,
                         unsigned short* __restrict__ h, int n) {
    int i = blockIdx.x * 256 + threadIdx.x;
    if (i >= n * 16) return;
    int node = i >> 4, c8 = (i & 15) << 3;
    const float* e = embed + ((size_t)x[node] << 7) + c8;
    float4 f0 = *(const float4*)e;
    float4 f1 = *(const float4*)(e + 4);
    uint4 o4;
    o4.x = (unsigned)f2b(f0.x) | ((unsigned)f2b(f0.y) << 16);
    o4.y = (unsigned)f2b(f0.z) | ((unsigned)f2b(f0.w) << 16);
    o4.z = (unsigned)f2b(f1.x) | ((unsigned)f2b(f1.y) << 16);
    o4.w = (unsigned)f2b(f1.z) | ((unsigned)f2b(f1.w) << 16);
    *(uint4*)(h + ((size_t)node << 7) + c8) = o4;
}
// AB[l][0][j]=scale, AB[l][1][j]=shift  (BN folded with conv bias; layer2: identity+bias)
__global__ void prep_bn_k(const float* __restrict__ conv_b,
                          const float* __restrict__ bn_g, const float* __restrict__ bn_b,
                          const float* __restrict__ bn_m, const float* __restrict__ bn_v,
                          float* __restrict__ AB) {
    int t = blockIdx.x * 128 + threadIdx.x;
    if (t >= 384) return;
    int l = t >> 7, j = t & 127;
    float A = 1.f, Bv = conv_b[(l << 7) + j];
    if (l < 2) {
        float sc = bn_g[(l << 7) + j] * rsqrtf(bn_v[(l << 7) + j] + EPSBN);
        A = sc;
        Bv = Bv * sc + (bn_b[(l << 7) + j] - bn_m[(l << 7) + j] * sc);
    }
    AB[(l << 8) + j] = A;
    AB[(l << 8) + 128 + j] = Bv;
}

#define PAIRF(w) ((f32x2){uhi2f((w) << 16), uhi2f((w) & 0xffff0000u)})
#define ACCP(b, u) { av2[(b)+0] += PAIRF((u).x); av2[(b)+1] += PAIRF((u).y); \
                     av2[(b)+2] += PAIRF((u).z); av2[(b)+3] += PAIRF((u).w); }

// ---------------- fused RGCN layer: no LDS, no barriers ----------------
// A-fragments aggregated in registers; B-fragments read straight from global
// (fragment-major wall -> 16B/lane coalesced, W is 32KB -> L2-resident).
// list_a/list_b non-null => compute only listed nodes (layer 3: home|away),
// output written compactly by list position.
__global__ __launch_bounds__(256, 4) void layer_k(
    const unsigned short* __restrict__ h_in,   // bf16 [N][128]
    unsigned short* __restrict__ h_out,        // bf16 [nout][128]
    const unsigned short* __restrict__ wfrag,  // bf16 [8][32][512]
    const float* __restrict__ AB,              // [2][128] scale,shift
    const int* __restrict__ seg_ptr, const int* __restrict__ src_sorted,
    const int* __restrict__ list_a, const int* __restrict__ list_b, int listB,
    int nout, int bnrelu)
{
    const int tid  = threadIdx.x;
    const int wave = tid >> 6;
    const int lane = tid & 63;
    const int n16  = lane & 15;
    const int quad = lane >> 4;
    const int row0 = blockIdx.x << 6;
    const int gidx = row0 + (wave << 4) + n16;   // output row
    const bool valid = gidx < nout;
    int gnode = 0;
    if (valid) {
        gnode = list_a ? (gidx < listB ? list_a[gidx] : list_b[gidx - listB]) : gidx;
    }
    const int segbase = gnode * RR;

    f32x4 acc[8];
#pragma unroll
    for (int i = 0; i < 8; ++i) acc[i] = (f32x4){0.f, 0.f, 0.f, 0.f};

    int ecur = valid ? seg_ptr[segbase] : 0;

    const unsigned short* wl = wfrag + (lane << 3);

    for (int kb = 0; kb < 8; ++kb) {
        // ---- gather ----
        f32x2 av2[16];
#pragma unroll
        for (int i = 0; i < 16; ++i) av2[i] = (f32x2){0.f, 0.f};
        float scale = 1.f;
        if (valid) {
            int e0, e1;
            if (kb < RR) {
                e0 = ecur;
                e1 = seg_ptr[segbase + kb + 1];
                ecur = e1;
                int c = e1 - e0;
                if (c > 0) scale = __builtin_amdgcn_rcpf((float)c);
            } else { e0 = 0; e1 = 1; }
            for (int e = e0; e < e1; ++e) {
                int s = (kb < RR) ? src_sorted[e] : gnode;
                const unsigned short* hp = h_in + ((size_t)s << 7) + (quad << 3);
                uint4 u0 = *(const uint4*)(hp);
                uint4 u1 = *(const uint4*)(hp + 32);
                uint4 u2 = *(const uint4*)(hp + 64);
                uint4 u3 = *(const uint4*)(hp + 96);
                ACCP(0, u0); ACCP(4, u1); ACCP(8, u2); ACCP(12, u3);
            }
        }
        // ---- convert to bf16 A-fragments ----
        uint4 au[4];
#pragma unroll
        for (int ks = 0; ks < 4; ++ks) {
            unsigned pw[4];
#pragma unroll
            for (int m = 0; m < 4; ++m) {
                f32x2 q = av2[(ks << 2) + m] * scale;
                __hip_bfloat162 b2 = __float22bfloat162_rn(make_float2(q.x, q.y));
                unsigned u; __builtin_memcpy(&u, &b2, 4);
                pw[m] = u;
            }
            au[ks].x = pw[0]; au[ks].y = pw[1]; au[ks].z = pw[2]; au[ks].w = pw[3];
        }
        // ---- MFMA, B-fragments from global (L2) ----
        const unsigned short* wk = wl + (kb << 14);
#pragma unroll
        for (int ks = 0; ks < 4; ++ks) {
            bf16x8 af;
            __builtin_memcpy(&af, &au[ks], 16);
#pragma unroll
            for (int nt = 0; nt < 8; ++nt) {
                bf16x8 bfr = *(const bf16x8*)(wk + (((ks << 3) + nt) << 9));
                acc[nt] = __builtin_amdgcn_mfma_f32_16x16x32_bf16(af, bfr, acc[nt], 0, 0, 0);
            }
        }
    }

    // epilogue: v = acc*A + B (BN+bias folded), ReLU, store bf16
    // C/D layout: col = lane&15, row = (lane>>4)*4 + reg
#pragma unroll
    for (int nt = 0; nt < 8; ++nt) {
        int j = (nt << 4) + n16;
        float Aj = AB[j];
        float Bj = AB[128 + j];
#pragma unroll
        for (int r = 0; r < 4; ++r) {
            int orow = row0 + (wave << 4) + (quad << 2) + r;
            if (orow < nout) {
                float v = acc[nt][r] * Aj + Bj;
                if (bnrelu) v = fmaxf(v, 0.f);
                h_out[((size_t)orow << 7) + j] = f2b(v);
            }
        }
    }
}

// ---------------- MLP head: 16 rows/block; hC is compact [2B][128] ----------------
__global__ __launch_bounds__(256) void mlp_k(
    const unsigned short* __restrict__ hC,
    const float* __restrict__ w0, const float* __restrict__ bb0,
    const float* __restrict__ w1, const float* __restrict__ bb1,
    const float* __restrict__ w2, const float* __restrict__ bb2,
    float* __restrict__ out, int Bn)
{
    __shared__ __attribute__((aligned(16))) float g0[16][256];
    __shared__ __attribute__((aligned(16))) float g1[16][256];
    __shared__ float lg[16][4];
    int t = threadIdx.x;
    {
        int row = t >> 4;
        int cseg = (t & 15) << 4;
        int gr = (blockIdx.x << 4) + row;
        int gc = (gr < Bn) ? gr : 0;
        const unsigned short* sp = (cseg < 128) ? (hC + ((size_t)gc << 7) + cseg)
                                                : (hC + ((size_t)(Bn + gc) << 7) + (cseg - 128));
#pragma unroll
        for (int c8 = 0; c8 < 2; ++c8) {
            uint4 v = *(const uint4*)(sp + (c8 << 3));
            int base = cseg + (c8 << 3);
            g0[row][base+0] = uhi2f(v.x << 16); g0[row][base+1] = uhi2f(v.x & 0xffff0000u);
            g0[row][base+2] = uhi2f(v.y << 16); g0[row][base+3] = uhi2f(v.y & 0xffff0000u);
            g0[row][base+4] = uhi2f(v.z << 16); g0[row][base+5] = uhi2f(v.z & 0xffff0000u);
            g0[row][base+6] = uhi2f(v.w << 16); g0[row][base+7] = uhi2f(v.w & 0xffff0000u);
        }
    }
    __syncthreads();
    {   // fc0
        float acc[16];
#pragma unroll
        for (int r = 0; r < 16; ++r) acc[r] = 0.f;
        const float* wr = w0 + (t << 8);
        for (int i = 0; i < 256; i += 4) {
            float4 w = *(const float4*)(wr + i);
#pragma unroll
            for (int r = 0; r < 16; ++r) {
                float4 g = *(const float4*)&g0[r][i];
                acc[r] += w.x * g.x + w.y * g.y + w.z * g.z + w.w * g.w;
            }
        }
        float bb = bb0[t];
#pragma unroll
        for (int r = 0; r < 16; ++r) g1[r][t] = fmaxf(acc[r] + bb, 0.f);
    }
    __syncthreads();
    {   // fc1
        int o = t & 127, rg = t >> 7;
        float acc[8];
#pragma unroll
        for (int r = 0; r < 8; ++r) acc[r] = 0.f;
        const float* wr = w1 + (o << 8);
        for (int i = 0; i < 256; i += 4) {
            float4 w = *(const float4*)(wr + i);
#pragma unroll
            for (int r = 0; r < 8; ++r) {
                float4 g = *(const float4*)&g1[(rg << 3) + r][i];
                acc[r] += w.x * g.x + w.y * g.y + w.z * g.z + w.w * g.w;
            }
        }
        float bb = bb1[o];
#pragma unroll
        for (int r = 0; r < 8; ++r) g0[(rg << 3) + r][o] = fmaxf(acc[r] + bb, 0.f);
    }
    __syncthreads();
    if (t < 48) {   // fc2
        int row = t / 3, cls = t - row * 3;
        const float* wr = w2 + (cls << 7);
        float a = 0.f;
        for (int i = 0; i < 128; i += 4) {
            float4 w = *(const float4*)(wr + i);
            float4 g = *(const float4*)&g0[row][i];
            a += w.x * g.x + w.y * g.y + w.z * g.z + w.w * g.w;
        }
        lg[row][cls] = a + bb2[cls];
    }
    __syncthreads();
    if (t < 16) {   // log_softmax + store
        int gr = (blockIdx.x << 4) + t;
        if (gr < Bn) {
            float l0 = lg[t][0], l1 = lg[t][1], l2 = lg[t][2];
            float m = fmaxf(l0, fmaxf(l1, l2));
            float lse = m + logf(expf(l0 - m) + expf(l1 - m) + expf(l2 - m));
            out[gr * 3 + 0] = l0 - lse;
            out[gr * 3 + 1] = l1 - lse;
            out[gr * 3 + 2] = l2 - lse;
        }
    }
}

extern "C" void kernel_launch(void* const* d_in, const int* in_sizes, int n_in,
                              void* d_out, int out_size, void* d_ws, size_t ws_size,
                              hipStream_t stream) {
    const int*   x      = (const int*)d_in[0];
    const int*   eidx   = (const int*)d_in[1];   // [2, E]
    const int*   etype  = (const int*)d_in[2];
    const int*   home   = (const int*)d_in[3];
    const int*   away   = (const int*)d_in[4];
    const float* embed  = (const float*)d_in[5];
    const float* rel_w  = (const float*)d_in[6];
    const float* root_w = (const float*)d_in[7];
    const float* conv_b = (const float*)d_in[8];
    const float* bn_g   = (const float*)d_in[9];
    const float* bn_b   = (const float*)d_in[10];
    const float* bn_m   = (const float*)d_in[11];
    const float* bn_v   = (const float*)d_in[12];
    const float* fc0w   = (const float*)d_in[13];
    const float* fc0b   = (const float*)d_in[14];
    const float* fc1w   = (const float*)d_in[15];
    const float* fc1b   = (const float*)d_in[16];
    const float* fc2w   = (const float*)d_in[17];
    const float* fc2b   = (const float*)d_in[18];
    float* out = (float*)d_out;

    const int N_ = in_sizes[0];
    const int E_ = in_sizes[2];
    const int B_ = in_sizes[3];
    const int NS = N_ * RR;

    char* ws = (char*)d_ws;
    auto alloc = [&](size_t bytes) -> char* {
        char* p = ws;
        ws += (bytes + 255) & ~(size_t)255;
        return p;
    };
    int* ptr         = (int*)alloc((size_t)(NS + 1) * 4);
    int* cursor      = (int*)alloc((size_t)NS * 4);
    int* bsum        = (int*)alloc(4096);
    int* src_sorted  = (int*)alloc((size_t)E_ * 4);
    unsigned short* wall = (unsigned short*)alloc((size_t)3 * 8 * 16384 * 2);
    unsigned short* hA   = (unsigned short*)alloc((size_t)N_ * 128 * 2);
    unsigned short* hB   = (unsigned short*)alloc((size_t)N_ * 128 * 2);
    unsigned short* hC   = (unsigned short*)alloc((size_t)2 * B_ * 128 * 2);
    float* AB        = (float*)alloc(3 * 256 * 4);

    const int nb = (NS + 1023) / 1024;

    // CSR build (segments constant across layers)
    (void)hipMemsetAsync(cursor, 0, (size_t)NS * 4, stream);
    hist_k<<<(E_ + 255) / 256, 256, 0, stream>>>(eidx + E_, etype, cursor, E_);
    scan1_k<<<nb, 256, 0, stream>>>(cursor, bsum, NS);
    scan2_k<<<1, 256, 0, stream>>>(bsum, nb);
    scan3_k<<<nb, 256, 0, stream>>>(cursor, bsum, ptr, cursor, NS, E_);
    scatter_k<<<(E_ + 255) / 256, 256, 0, stream>>>(eidx, eidx + E_, etype, cursor, src_sorted, E_);

    // weight + feature + BN prep
    prep_w_k<<<24, 256, 0, stream>>>(rel_w, root_w, wall);
    prep_h_k<<<(N_ * 16 + 255) / 256, 256, 0, stream>>>(x, embed, hA, N_);
    prep_bn_k<<<3, 128, 0, stream>>>(conv_b, bn_g, bn_b, bn_m, bn_v, AB);

    const int lgrid = (N_ + 63) / 64;
    layer_k<<<lgrid, 256, 0, stream>>>(hA, hB, wall + 0 * 8 * 16384, AB + 0,
                                       ptr, src_sorted, nullptr, nullptr, 0, N_, 1);
    layer_k<<<lgrid, 256, 0, stream>>>(hB, hA, wall + 1 * 8 * 16384, AB + 256,
                                       ptr, src_sorted, nullptr, nullptr, 0, N_, 1);
    // layer 3: only home|away rows, compact output
    const int n3 = 2 * B_;
    layer_k<<<(n3 + 63) / 64, 256, 0, stream>>>(hA, hC, wall + 2 * 8 * 16384, AB + 512,
                                                ptr, src_sorted, home, away, B_, n3, 0);

    mlp_k<<<(B_ + 15) / 16, 256, 0, stream>>>(hC, fc0w, fc0b, fc1w, fc1b,
                                              fc2w, fc2b, out, B_);
}